// Round 12
// baseline (311.881 us; speedup 1.0000x reference)
//
#include <hip/hip_runtime.h>

// ---------------------------------------------------------------------------
// AttentionTemporalEncoder on MI355X (gfx950)
// B=32, T=512, HIDDEN=1024, NH=16, HD=64
//
// R25: re-land R22's 2-round gemm1 (profiled 78.0us, MfmaUtil 35.7) + tail
// kernel; R22's total regression was a rest-outlier (R24 established total
// noise ~±10us; "rest" is ~205us in 6/8 rounds, R22's 241 was the outlier,
// while its gemm1 counter profile was the best ever measured).
//  - gemm1 grid 512, ALL live, exactly 2 rounds; K/V blocks cover cols
//    [0,256); gemm1_tail covers [256,Tc); prep zero-fills [Tc,ceil64).
//  - NEW: OcT aliases QT (-32 MB workspace). Safe: each attn block reads
//    its QT region fully (drained before barrier) before writing the same
//    region as OcT; attn overwrites all of QT before gemm2 reads it.
// scan/prep/attn/gemm2/final byte-identical to R24.
// ---------------------------------------------------------------------------

typedef _Float16 half8 __attribute__((ext_vector_type(8)));
typedef _Float16 half4 __attribute__((ext_vector_type(4)));
typedef float floatx4 __attribute__((ext_vector_type(4)));
typedef unsigned uintx2 __attribute__((ext_vector_type(2)));

#define HID 1024
#define TT 512
#define NB 32
#define QSCALE 0.1803368801111244f   /* 0.125 * log2(e) */
#define SB2 72.13475204444817f       /* 50 * log2(e)    */

__device__ __forceinline__ void gload16(const void* g, void* l) {
    __builtin_amdgcn_global_load_lds(
        (const __attribute__((address_space(1))) unsigned int*)g,
        (__attribute__((address_space(3))) unsigned int*)l, 16, 0, 0);
}

// monotone float->uint key: preserves order for atomicMax; 0 is below all keys
__device__ __forceinline__ unsigned fkey(float f) {
    unsigned u = __float_as_uint(f);
    return (u & 0x80000000u) ? ~u : (u | 0x80000000u);
}
__device__ __forceinline__ float funkey(unsigned k) {
    unsigned u = (k & 0x80000000u) ? (k ^ 0x80000000u) : ~k;
    return __uint_as_float(u);
}

// ---------------------------------------------------------------------------
// scan: one block per batch. cpa[b][t] = permuted position; Tcg[b] = #unmasked.
__global__ __launch_bounds__(256) void scan_kernel(
    const int* __restrict__ mask, short* __restrict__ cpa,
    int* __restrict__ Tcg)
{
    __shared__ int wsum[4];
    const int b = blockIdx.x;
    const int* mrow = mask + b * TT;
    const int tid = threadIdx.x;
    const int lane = tid & 63, wv = tid >> 6;
    const int m0 = mrow[tid * 2] ? 1 : 0;
    const int m1 = mrow[tid * 2 + 1] ? 1 : 0;
    const int ps = m0 + m1;
    int v = ps;
    for (int d = 1; d < 64; d <<= 1) {
        int u = __shfl_up(v, d, 64);
        if (lane >= d) v += u;
    }
    if (lane == 63) wsum[wv] = v;
    __syncthreads();
    int off = 0;
    for (int i = 0; i < 4; i++) off += (i < wv) ? wsum[i] : 0;
    const int total = wsum[0] + wsum[1] + wsum[2] + wsum[3];
    const int excl0 = off + v - ps;              // unmasked in [0, 2*tid)
    const int t0 = tid * 2, t1 = t0 + 1;
    const int excl1 = excl0 + m0;
    const int p0 = m0 ? excl0 : total + (t0 - excl0);
    const int p1 = m1 ? excl1 : total + (t1 - excl1);
    cpa[(size_t)b * TT + t0] = (short)p0;
    cpa[(size_t)b * TT + t1] = (short)p1;
    if (tid == 255) Tcg[b] = total;
}

// ---------------------------------------------------------------------------
// prep: [0,4096) convw (Q sec pre-scaled), [4096,8192) xpose 64x64 writing
// permuted xP rows, [8192,8320) initmax, [8320,8324) bqs,
// [8324,8580) KT/Vb tail zero-fill (8 slices per batch, uses Tcg).
__global__ __launch_bounds__(256) void prep_kernel(
    const float* __restrict__ Wq, const float* __restrict__ Wk,
    const float* __restrict__ Wv, const float* __restrict__ Wo,
    _Float16* __restrict__ Wcat,
    const float* __restrict__ x, _Float16* __restrict__ xP,
    unsigned* __restrict__ omax,
    const float* __restrict__ bq, float* __restrict__ bqs,
    const short* __restrict__ cpa, const int* __restrict__ Tcg,
    _Float16* __restrict__ KT, _Float16* __restrict__ Vb)
{
    __shared__ float tile[64][65];
    const int bid = blockIdx.x;
    if (bid < 4096) {
        int i4 = bid * 256 + threadIdx.x;        // float4 index, 0 .. 1M
        int sec = i4 >> 18;
        int off4 = i4 & ((1 << 18) - 1);
        const float* src = (sec == 0) ? Wq : (sec == 1) ? Wk
                          : (sec == 2) ? Wv : Wo;
        float4 v = ((const float4*)src)[off4];
        if (sec == 0) {
            v.x *= QSCALE; v.y *= QSCALE; v.z *= QSCALE; v.w *= QSCALE;
        }
        half4 h = {(_Float16)v.x, (_Float16)v.y, (_Float16)v.z, (_Float16)v.w};
        *(half4*)(Wcat + (size_t)i4 * 4) = h;
    } else if (bid < 8192) {
        int idx = bid - 4096;                    // 32 b x 16 h-tiles x 8 t-tiles
        int b = idx >> 7, h0 = ((idx >> 3) & 15) * 64, t0 = (idx & 7) * 64;
        int tx = threadIdx.x & 15, ty = threadIdx.x >> 4;   // 16x16
        const float* xb = x + ((size_t)b * HID + h0) * TT + t0;
        for (int p = 0; p < 4; p++) {
            int r = ty + 16 * p;
            float4 v = *(const float4*)(xb + (size_t)r * TT + tx * 4);
            tile[r][tx * 4 + 0] = v.x;
            tile[r][tx * 4 + 1] = v.y;
            tile[r][tx * 4 + 2] = v.z;
            tile[r][tx * 4 + 3] = v.w;
        }
        __syncthreads();
        int hc = (threadIdx.x & 7) * 8, tb = threadIdx.x >> 3;  // 8 x 32
        for (int rd = 0; rd < 2; rd++) {
            int tt = tb + 32 * rd;
            half8 pk;
            for (int k = 0; k < 8; k++)
                pk[k] = (_Float16)tile[hc + k][tt];
            short ct = cpa[b * TT + t0 + tt];
            *(half8*)(xP + ((size_t)b * TT + ct) * HID + h0 + hc) = pk;
        }
    } else if (bid < 8320) {
        omax[(bid - 8192) * 256 + threadIdx.x] = 0u;
    } else if (bid < 8324) {
        int i = (bid - 8320) * 256 + threadIdx.x;   // 0..1023
        bqs[i] = bq[i] * QSCALE;
    } else {
        // KT/Vb tail zero-fill, 8 slices per batch
        const int idx = bid - 8324;              // 0..255
        const int b = idx >> 3, sl = idx & 7;
        const int tid = threadIdx.x;
        const int Tc = Tcg[b];
        const int ce = (Tc + 63) & ~63;
        const int nrow = ce - Tc;                // 0..63
        // KT rows [Tc, ce), cols [sl*128, sl*128+128): half8 stores
        half8 z8 = {};
        for (int i = tid; i < nrow * 16; i += 256) {
            int r = i >> 4, c8 = i & 15;
            *(half8*)(KT + ((size_t)b * TT + Tc + r) * HID +
                      sl * 128 + c8 * 8) = z8;
        }
        // Vb o-rows [sl*128, (sl+1)*128), cols [Tc, ce): scalar
        const int o = sl * 128 + (tid >> 1);
        const int half0 = (tid & 1) * ((nrow + 1) >> 1);
        const int cnt = (tid & 1) ? (nrow - ((nrow + 1) >> 1))
                                  : ((nrow + 1) >> 1);
        _Float16* vr = Vb + ((size_t)b * HID + o) * TT + Tc + half0;
        for (int j = 0; j < cnt; j++) vr[j] = (_Float16)0.f;
    }
}

// ---------------------------------------------------------------------------
// 256x256 8-phase mainloop (R14-verified). C(256x256) += A(256xK) * B^T,
// both row-major, K contig, lda = ldb = 1024. 512 threads = 8 waves (2Mx4N),
// per-wave output 128x64 = acc[8][4]. LDS 128 KiB double-buffered; granule
// swizzle via pre-swizzled global source; counted vmcnt(10), drain 10->0.
#define PH_PRE do { \
    __builtin_amdgcn_s_barrier(); \
    asm volatile("s_waitcnt lgkmcnt(0)" ::: "memory"); \
    __builtin_amdgcn_sched_barrier(0); \
    __builtin_amdgcn_s_setprio(1); \
} while (0)

#define PH_POST(N) do { \
    __builtin_amdgcn_s_setprio(0); \
    asm volatile("s_waitcnt vmcnt(" #N ")" ::: "memory"); \
    __builtin_amdgcn_s_barrier(); \
} while (0)

#define LDA(P, MH) do { \
    const _Float16* ab_ = lds + (P) * 16384 + (MH) * 8192 + aoff; \
    af[0][0] = *(const half8*)(ab_ + pb0); \
    af[0][1] = *(const half8*)(ab_ + pb1); \
    af[1][0] = *(const half8*)(ab_ + 1024 + pb0); \
    af[1][1] = *(const half8*)(ab_ + 1024 + pb1); \
    af[2][0] = *(const half8*)(ab_ + 2048 + pb0); \
    af[2][1] = *(const half8*)(ab_ + 2048 + pb1); \
    af[3][0] = *(const half8*)(ab_ + 3072 + pb0); \
    af[3][1] = *(const half8*)(ab_ + 3072 + pb1); \
} while (0)

#define LDB(P, NH) do { \
    const _Float16* bb_ = lds + 32768 + (P) * 16384 + (NH) * 8192 + boff; \
    bf[NH][0][0] = *(const half8*)(bb_ + pb0); \
    bf[NH][0][1] = *(const half8*)(bb_ + pb1); \
    bf[NH][1][0] = *(const half8*)(bb_ + 1024 + pb0); \
    bf[NH][1][1] = *(const half8*)(bb_ + 1024 + pb1); \
} while (0)

#define MFMAQ(MH, NH) do { \
    _Pragma("unroll") \
    for (int j_ = 0; j_ < 4; ++j_) { \
        _Pragma("unroll") \
        for (int n_ = 0; n_ < 2; ++n_) { \
            floatx4 c_ = acc[(MH) * 4 + j_][(NH) * 2 + n_]; \
            c_ = __builtin_amdgcn_mfma_f32_16x16x32_f16( \
                af[j_][0], bf[NH][n_][0], c_, 0, 0, 0); \
            c_ = __builtin_amdgcn_mfma_f32_16x16x32_f16( \
                af[j_][1], bf[NH][n_][1], c_, 0, 0, 0); \
            acc[(MH) * 4 + j_][(NH) * 2 + n_] = c_; \
        } \
    } \
} while (0)

#define STAGE_A(P, MH, K0) do { \
    _Float16* d_ = lds + (P) * 16384 + (MH) * 8192 + wst; \
    gload16(ag + (MH) * 65536 + (K0), d_); \
    gload16(ag + 131072 + (MH) * 65536 + (K0), d_ + 4096); \
} while (0)

#define STAGE_B(P, NH, K0) do { \
    _Float16* d_ = lds + 32768 + (P) * 16384 + (NH) * 8192 + wst; \
    gload16(bg + (NH) * 32768 + (K0), d_); \
    gload16(bg + 131072 + (NH) * 32768 + (K0), d_ + 4096); \
} while (0)

__device__ __forceinline__ void mainloop256(
    const _Float16* __restrict__ Ag,   // A + m0*1024 (rows m, K contig)
    const _Float16* __restrict__ Bg,   // act + n0*1024 (rows n, K contig)
    _Float16* lds, floatx4 acc[8][4], int tid)
{
    const int lane = tid & 63;
    const int w = tid >> 6, wr = w >> 2, wc = w & 3;
    const int l15 = lane & 15, quad = lane >> 4;
    const int pa = quad ^ (l15 & 7);
    const int pb0 = pa * 8, pb1 = (pa ^ 4) * 8;
    const int aoff = (wr * 64 + l15) * 64;
    const int boff = (wc * 32 + l15) * 64;
    const int wst = w * 512;                    // wave-uniform LDS stage base
    const int r = tid >> 3;                     // 0..63
    const int sg = (tid & 7) ^ (r & 7);         // pre-swizzled source granule
    const int nbase = ((r >> 5) << 6) + (r & 31);
    const _Float16* ag = Ag + (size_t)r * 1024 + sg * 8;
    const _Float16* bg = Bg + (size_t)nbase * 1024 + sg * 8;

    half8 af[4][2], bf[2][2][2];

    STAGE_A(0, 0, 0); STAGE_B(0, 0, 0); STAGE_B(0, 1, 0); STAGE_A(0, 1, 0);
    STAGE_A(1, 0, 64); STAGE_B(1, 0, 64); STAGE_B(1, 1, 64);
    asm volatile("s_waitcnt vmcnt(10)" ::: "memory");
    __builtin_amdgcn_s_barrier();

    for (int i = 0; i < 7; ++i) {
        const int kb = i * 128 + 64;
        const int kn0 = kb + 64, kn1 = kb + 128;
        LDA(0, 0); LDB(0, 0); STAGE_A(1, 1, kb);
        PH_PRE; MFMAQ(0, 0); PH_POST(10);
        LDB(0, 1);            STAGE_A(0, 0, kn0);
        PH_PRE; MFMAQ(0, 1); PH_POST(10);
        LDA(0, 1);            STAGE_B(0, 0, kn0);
        PH_PRE; MFMAQ(1, 1); PH_POST(10);
                              STAGE_B(0, 1, kn0);
        PH_PRE; MFMAQ(1, 0); PH_POST(10);
        LDA(1, 0); LDB(1, 0); STAGE_A(0, 1, kn0);
        PH_PRE; MFMAQ(0, 0); PH_POST(10);
        LDB(1, 1);            STAGE_A(1, 0, kn1);
        PH_PRE; MFMAQ(0, 1); PH_POST(10);
        LDA(1, 1);            STAGE_B(1, 0, kn1);
        PH_PRE; MFMAQ(1, 1); PH_POST(10);
                              STAGE_B(1, 1, kn1);
        PH_PRE; MFMAQ(1, 0); PH_POST(10);
    }
    LDA(0, 0); LDB(0, 0); STAGE_A(1, 1, 960);
    PH_PRE; MFMAQ(0, 0); PH_POST(10);
    LDB(0, 1);
    PH_PRE; MFMAQ(0, 1); PH_POST(8);
    LDA(0, 1);
    PH_PRE; MFMAQ(1, 1); PH_POST(6);
    PH_PRE; MFMAQ(1, 0); PH_POST(4);
    LDA(1, 0); LDB(1, 0);
    PH_PRE; MFMAQ(0, 0); PH_POST(2);
    LDB(1, 1);
    PH_PRE; MFMAQ(0, 1); PH_POST(0);
    LDA(1, 1);
    PH_PRE; MFMAQ(1, 1); MFMAQ(1, 0);
    __builtin_amdgcn_s_setprio(0);
}

// gemm1. 1-D grid 512, ALL blocks live, exactly 2 per CU.
// Per XCD: 4 batches x {r<8: Q m-tile (r>>1), n0=(r&1)*256 | r>=8: K/V
// m-tile (r-8), n0=0}. Tail cols [256,Tc) handled by gemm1_tail_kernel.
__global__ __launch_bounds__(512, 2) void gemm1_kernel(
    const _Float16* __restrict__ Wcat,
    const float* __restrict__ bqs, const float* __restrict__ bk,
    const float* __restrict__ bv,
    const _Float16* __restrict__ xP,
    _Float16* __restrict__ QT, _Float16* __restrict__ KT,
    _Float16* __restrict__ Vb, const int* __restrict__ Tcg)
{
    __shared__ __align__(16) _Float16 smem[65536];   // 128 KiB
    const int tid = threadIdx.x;
    const int id = blockIdx.x;
    const int xcd = id & 7, slot = id >> 3;      // slot 0..63
    const int bb = xcd * 4 + (slot >> 4);
    const int rsl = slot & 15;
    const int m0 = (rsl < 8) ? (rsl >> 1) * 256 : 1024 + (rsl - 8) * 256;
    const int n0 = (rsl < 8) ? (rsl & 1) * 256 : 0;
    const int lane = tid & 63;
    const int w = tid >> 6, wr = w >> 2, wc = w & 3;
    const int l15 = lane & 15, quad = lane >> 4;

    const int sec = m0 >> 10;          // 0=q 1=k 2=v (uniform per block)
    const int Tc = Tcg[bb];

    floatx4 acc[8][4] = {};
    mainloop256(Wcat + (size_t)m0 * 1024,
                xP + ((size_t)bb * TT + n0) * HID, smem, acc, tid);
    __syncthreads();

    const int mo = m0 & 1023;

    if (sec < 2) {
        const float* bias = (sec == 0) ? bqs : bk;
        _Float16* dst = (sec == 0) ? QT : KT;
        _Float16* tr = smem;                       // [256][136] halves
        for (int h = 0; h < 2; ++h) {
            if (wr == h) {
                for (int mi = 0; mi < 8; ++mi) {
                    float bs[4];
                    for (int rr = 0; rr < 4; ++rr)
                        bs[rr] = bias[mo + h * 128 + mi * 16 + quad * 4 + rr];
                    for (int ni = 0; ni < 4; ++ni) {
                        half4 pk;
                        for (int rr = 0; rr < 4; ++rr)
                            pk[rr] = (_Float16)(acc[mi][ni][rr] + bs[rr]);
                        *(half4*)(tr + (wc * 64 + ni * 16 + l15) * 136 +
                                  mi * 16 + quad * 4) = pk;
                    }
                }
            }
            __syncthreads();
            const int row = tid >> 4, off = (tid & 15) * 8;
            for (int s = 0; s < 8; ++s) {
                int trow = n0 + row + 32 * s;
                uint4 v = *(uint4*)(tr + (row + 32 * s) * 136 + off);
                if (sec == 0 || trow < Tc)
                    *(uint4*)(dst + ((size_t)bb * TT + trow) * HID +
                              mo + h * 128 + off) = v;
            }
            __syncthreads();
        }
    } else {
        for (int mi = 0; mi < 8; ++mi) {
            float bs[4];
            for (int rr = 0; rr < 4; ++rr)
                bs[rr] = bv[mo + wr * 128 + mi * 16 + quad * 4 + rr];
            for (int ni = 0; ni < 4; ++ni) {
                int t = n0 + wc * 64 + ni * 16 + l15;   // already compacted
                if (t >= Tc) continue;
                for (int rr = 0; rr < 4; ++rr) {
                    int o = mo + wr * 128 + mi * 16 + quad * 4 + rr;
                    Vb[((size_t)bb * HID + o) * TT + t] =
                        (_Float16)(acc[mi][ni][rr] + bs[rr]);
                }
            }
        }
    }
}

// ---------------------------------------------------------------------------
// gemm1_tail: K/V projections for key cols [256, Tc) (only when Tc > 256).
// Grid 512: per XCD 4 batches x 16 m-slices (128 rows of K+V range
// [1024,3072)). LDS-free: MFMA operands straight from global (L2-resident).
__global__ __launch_bounds__(256) void gemm1_tail_kernel(
    const _Float16* __restrict__ Wcat,
    const float* __restrict__ bk, const float* __restrict__ bv,
    const _Float16* __restrict__ xP,
    _Float16* __restrict__ KT, _Float16* __restrict__ Vb,
    const int* __restrict__ Tcg)
{
    const int id = blockIdx.x;
    const int xcd = id & 7, slot = id >> 3;       // 0..63
    const int bb = xcd * 4 + (slot >> 4);
    const int ms = slot & 15;
    const int Tc = Tcg[bb];
    if (Tc <= 256) return;
    const int m0 = 1024 + ms * 128;               // K: ms<8, V: ms>=8
    const int mo = m0 & 1023;
    const int tid = threadIdx.x;
    const int lane = tid & 63, w = tid >> 6;      // 4 waves x 32 m-rows
    const int l15 = lane & 15, quad = lane >> 4;
    const float* bias = (m0 < 2048) ? bk : bv;

    const _Float16* ab = Wcat + (size_t)(m0 + w * 32 + l15) * 1024 + quad * 8;

    for (int c0 = 256; c0 < Tc; c0 += 64) {
        floatx4 acc[2][4] = {};
        const _Float16* bp = xP + ((size_t)bb * TT + c0 + l15) * 1024 + quad * 8;
        for (int k0 = 0; k0 < 1024; k0 += 64) {
            half8 a0[2], a1[2], b0[4], b1[4];
#pragma unroll
            for (int mi = 0; mi < 2; ++mi) {
                a0[mi] = *(const half8*)(ab + mi * 16384 + k0);
                a1[mi] = *(const half8*)(ab + mi * 16384 + k0 + 32);
            }
#pragma unroll
            for (int ni = 0; ni < 4; ++ni) {
                b0[ni] = *(const half8*)(bp + ni * 16384 + k0);
                b1[ni] = *(const half8*)(bp + ni * 16384 + k0 + 32);
            }
#pragma unroll
            for (int mi = 0; mi < 2; ++mi)
#pragma unroll
                for (int ni = 0; ni < 4; ++ni) {
                    acc[mi][ni] = __builtin_amdgcn_mfma_f32_16x16x32_f16(
                        a0[mi], b0[ni], acc[mi][ni], 0, 0, 0);
                    acc[mi][ni] = __builtin_amdgcn_mfma_f32_16x16x32_f16(
                        a1[mi], b1[ni], acc[mi][ni], 0, 0, 0);
                }
        }
        for (int mi = 0; mi < 2; ++mi) {
            const int ob = mo + w * 32 + mi * 16 + quad * 4;
            float bs[4];
            for (int rr = 0; rr < 4; ++rr) bs[rr] = bias[ob + rr];
            for (int ni = 0; ni < 4; ++ni) {
                int t = c0 + ni * 16 + l15;
                if (t >= Tc) continue;
                if (m0 < 2048) {
                    half4 pk;
                    for (int rr = 0; rr < 4; ++rr)
                        pk[rr] = (_Float16)(acc[mi][ni][rr] + bs[rr]);
                    *(half4*)(KT + ((size_t)bb * TT + t) * HID + ob) = pk;
                } else {
                    for (int rr = 0; rr < 4; ++rr)
                        Vb[((size_t)bb * HID + ob + rr) * TT + t] =
                            (_Float16)(acc[mi][ni][rr] + bs[rr]);
                }
            }
        }
    }
}

// ---------------------------------------------------------------------------
// attention: 8-wave 512-thread blocks, 256 q-rows each, grid 1024.
// K/V are compacted to the first Tc[b] columns; loop nt = ceil(Tc/64) tiles;
// tail columns >= Tc clamped to -50 (K/V tails are zero-filled by prep).
// NOTE: OcT aliases QT — each block reads its QT region fully before its
// OcT writes (read drained before the post-stage barrier), same region,
// single owner block; attn fully overwrites QT before gemm2 reads.
__global__ __launch_bounds__(512, 4) void attn_kernel(
    const _Float16* __restrict__ QT, const _Float16* __restrict__ KT,
    const _Float16* __restrict__ Vb, const int* __restrict__ Tcg,
    _Float16* __restrict__ OcT)
{
    __shared__ __align__(16) _Float16 kvbuf[4 * 4096];   // Q stage / K,V dbuf
    __shared__ __align__(16) _Float16 ps[2 * 8192];      // [qt][128 q][64 t]
    __shared__ __align__(16) float msf[2][64];           // clamp hi per t

    const int id = blockIdx.x;
    const int xcd = id & 7, slot = id >> 3;      // slot 0..127
    const int grp = xcd + 8 * (slot >> 1);       // 0..511 = hd + 16*b
    const int q0 = (slot & 1) * 256;
    const int hd = grp & 15, b = grp >> 4;
    const int tid = threadIdx.x;
    const int lane = tid & 63, wid = tid >> 6;   // wid 0..7
    const int l15 = lane & 15, quad = lane >> 4;

    const _Float16* QTb = QT + ((size_t)b * TT + q0) * HID + hd * 64;
    const _Float16* KTb = KT + (size_t)b * TT * HID + hd * 64;
    const _Float16* Vbb = Vb + ((size_t)b * HID + hd * 64) * TT;
    const int Tc = Tcg[b];
    const int nt = (Tc + 63) >> 6;

    const int srow = lane >> 3;                 // 0..7 == row&7
    const int sg = (lane & 7) ^ srow;
    const int pa = quad ^ (l15 & 7);
    const int pz = l15 & 7;

    // stage 256 Q rows (32 KB) into kvbuf, then lift fragments to registers
    for (int p = 0; p < 4; p++) {
        int r = p * 64 + wid * 8 + srow;
        gload16(QTb + (size_t)r * HID + sg * 8,
                kvbuf + (p * 64 + wid * 8) * 64);
    }
    __syncthreads();
    half8 bq[2][2];
    for (int qt = 0; qt < 2; qt++) {
        int qr = qt * 128 + wid * 16 + l15;
        bq[qt][0] = *(half8*)(kvbuf + qr * 64 + pa * 8);
        bq[qt][1] = *(half8*)(kvbuf + qr * 64 + (pa ^ 4) * 8);
    }
    __syncthreads();

    auto stage = [&](int jcn, int bufn) {
        int t0n = jcn * 64;
        _Float16* kd = kvbuf + bufn * 4096;
        _Float16* vd = kvbuf + (2 + bufn) * 4096;
        int r = wid * 8 + srow;
        gload16(KTb + (size_t)(t0n + r) * HID + sg * 8, kd + (wid * 8) * 64);
        gload16(Vbb + (size_t)r * TT + t0n + sg * 8, vd + (wid * 8) * 64);
        if (tid < 64) msf[bufn][tid] = (t0n + tid < Tc) ? SB2 : -SB2;
    };

    stage(0, 0);

    floatx4 oacc[2][4] = {};
    float rs[2] = {0.f, 0.f};
    const float lo = -SB2;

    for (int jc = 0; jc < nt; jc++) {
        const int cur = jc & 1;
        __syncthreads();
        if (jc < nt - 1) stage(jc + 1, 1 - cur);

        const _Float16* ks = kvbuf + cur * 4096;
        const _Float16* vs = kvbuf + (2 + cur) * 4096;

        for (int jt = 0; jt < 4; jt++) {
            half8 ka0 = *(half8*)(ks + (jt * 16 + l15) * 64 + pa * 8);
            half8 ka1 = *(half8*)(ks + (jt * 16 + l15) * 64 + (pa ^ 4) * 8);
            floatx4 hi = *(floatx4*)(&msf[cur][jt * 16 + quad * 4]);
            for (int qt = 0; qt < 2; qt++) {
                floatx4 sc = {0.f, 0.f, 0.f, 0.f};
                sc = __builtin_amdgcn_mfma_f32_16x16x32_f16(ka0, bq[qt][0], sc, 0, 0, 0);
                sc = __builtin_amdgcn_mfma_f32_16x16x32_f16(ka1, bq[qt][1], sc, 0, 0, 0);
                float e0 = __builtin_amdgcn_exp2f(fminf(fmaxf(sc[0], lo), hi[0]));
                float e1 = __builtin_amdgcn_exp2f(fminf(fmaxf(sc[1], lo), hi[1]));
                float e2 = __builtin_amdgcn_exp2f(fminf(fmaxf(sc[2], lo), hi[2]));
                float e3 = __builtin_amdgcn_exp2f(fminf(fmaxf(sc[3], lo), hi[3]));
                rs[qt] += (e0 + e1) + (e2 + e3);
                unsigned uA = __builtin_bit_cast(
                    unsigned, __builtin_amdgcn_cvt_pkrtz(e0, e1));
                unsigned uB = __builtin_bit_cast(
                    unsigned, __builtin_amdgcn_cvt_pkrtz(e2, e3));
                uintx2 uv = {uA, uB};
                half4 pk = __builtin_bit_cast(half4, uv);
                int g = jt * 2 + (quad >> 1);
                *(half4*)(ps + qt * 8192 + (wid * 16 + l15) * 64 + (g ^ pz) * 8 +
                          (quad & 1) * 4) = pk;
            }
        }
        for (int kc = 0; kc < 2; kc++) {
            int g = kc * 4 + quad;
            half8 bv8[4];
            for (int d4 = 0; d4 < 4; d4++)
                bv8[d4] = *(half8*)(vs + (d4 * 16 + l15) * 64 + (g ^ pz) * 8);
            for (int qt = 0; qt < 2; qt++) {
                half8 ap = *(half8*)(ps + qt * 8192 + (wid * 16 + l15) * 64 +
                                     (g ^ pz) * 8);
                for (int d4 = 0; d4 < 4; d4++)
                    oacc[qt][d4] = __builtin_amdgcn_mfma_f32_16x16x32_f16(
                        ap, bv8[d4], oacc[qt][d4], 0, 0, 0);
            }
        }
    }

    for (int qt = 0; qt < 2; qt++) {
        float s = rs[qt];
        s += __shfl_xor(s, 16, 64);
        s += __shfl_xor(s, 32, 64);
        s = 1.0f / s;
        float inv[4];
        for (int r = 0; r < 4; r++) inv[r] = __shfl(s, quad * 4 + r, 64);
        for (int d4 = 0; d4 < 4; d4++)
            for (int r = 0; r < 4; r++) {
                int t = q0 + qt * 128 + wid * 16 + quad * 4 + r;
                int c = hd * 64 + d4 * 16 + l15;
                OcT[((size_t)b * TT + t) * HID + c] =
                    (_Float16)(oacc[qt][d4][r] * inv[r]);
            }
    }
}

// ---------------------------------------------------------------------------
// gemm2. 1-D grid 256, XCD-clustered (4 m-tiles per n-group).
__global__ __launch_bounds__(512, 2) void gemm2_kernel(
    const _Float16* __restrict__ Wo16, const _Float16* __restrict__ OcT,
    unsigned* __restrict__ omax)
{
    __shared__ __align__(16) _Float16 smem[65536];
    _Float16* lds = smem;
    const int tid = threadIdx.x;
    const int id = blockIdx.x;
    const int xcd = id & 7, slot = id >> 3;      // slot 0..31
    const int grp = xcd + 8 * (slot >> 2);       // 0..63 = n0i + 2*b
    const int m0 = (slot & 3) * 256;
    const int n0 = (grp & 1) * 256;
    const int bb = grp >> 1;
    const int lane = tid & 63;
    const int w = tid >> 6, wr = w >> 2;
    const int l15 = lane & 15, quad = lane >> 4;

    floatx4 acc[8][4] = {};
    mainloop256(Wo16 + (size_t)m0 * 1024,
                OcT + ((size_t)bb * TT + n0) * HID, lds, acc, tid);

    for (int mi = 0; mi < 8; ++mi)
        for (int rr = 0; rr < 4; ++rr) {
            float v = acc[mi][0][rr];
            v = fmaxf(v, acc[mi][1][rr]);
            v = fmaxf(v, acc[mi][2][rr]);
            v = fmaxf(v, acc[mi][3][rr]);
            for (int d = 1; d < 16; d <<= 1)
                v = fmaxf(v, __shfl_xor(v, d, 64));
            if (l15 == 0) {
                int o = m0 + wr * 128 + mi * 16 + quad * 4 + rr;
                atomicMax(&omax[bb * HID + o], fkey(v));
            }
        }
}

__global__ __launch_bounds__(256) void final_kernel(
    const unsigned* __restrict__ omax, const float* __restrict__ bo,
    float* __restrict__ out)
{
    int i = blockIdx.x * 256 + threadIdx.x;   // 0 .. 32767
    out[i] = funkey(omax[i]) + bo[i & 1023];
}

// ---------------------------------------------------------------------------
extern "C" void kernel_launch(void* const* d_in, const int* in_sizes, int n_in,
                              void* d_out, int out_size, void* d_ws, size_t ws_size,
                              hipStream_t stream)
{
    const float* x  = (const float*)d_in[0];
    const int* mask = (const int*)d_in[1];
    const float* Wq = (const float*)d_in[2];
    const float* bq = (const float*)d_in[3];
    const float* Wk = (const float*)d_in[4];
    const float* bk = (const float*)d_in[5];
    const float* Wv = (const float*)d_in[6];
    const float* bv = (const float*)d_in[7];
    const float* Wo = (const float*)d_in[8];
    const float* bo = (const float*)d_in[9];
    float* out = (float*)d_out;

    char* ws = (char*)d_ws;
    _Float16* Wcat = (_Float16*)(ws);                      //   8 MiB (q,k,v,o)
    _Float16* xP   = (_Float16*)(ws + (8ull  << 20));      //  32 MiB (permuted)
    _Float16* QT   = (_Float16*)(ws + (40ull << 20));      //  32 MiB
    _Float16* KT   = (_Float16*)(ws + (72ull << 20));      //  32 MiB
    _Float16* Vb   = (_Float16*)(ws + (104ull << 20));     //  32 MiB
    _Float16* OcT  = QT;    // alias: attn reads QT fully before writing OcT
    unsigned* omax = (unsigned*)(ws + (136ull << 20));     // 128 KiB
    float*    bqs  = (float*)(ws + (136ull << 20) + (128ull << 10)); // 4 KiB
    short*    cpa  = (short*)(ws + (136ull << 20) + (132ull << 10)); // 32 KiB
    int*      Tcg  = (int*)  (ws + (136ull << 20) + (164ull << 10)); // 128 B

    scan_kernel<<<32, 256, 0, stream>>>(mask, cpa, Tcg);
    prep_kernel<<<8580, 256, 0, stream>>>(Wq, Wk, Wv, Wo, Wcat, x, xP,
                                          omax, bq, bqs, cpa, Tcg, KT, Vb);
    gemm1_kernel<<<512, 512, 0, stream>>>(Wcat, bqs, bk, bv, xP,
                                          QT, KT, Vb, Tcg);
    gemm1_tail_kernel<<<512, 256, 0, stream>>>(Wcat, bk, bv, xP, KT, Vb, Tcg);
    attn_kernel<<<1024, 512, 0, stream>>>(QT, KT, Vb, Tcg, OcT);
    gemm2_kernel<<<256, 512, 0, stream>>>(Wcat + (3ull << 20), OcT, omax);
    final_kernel<<<128, 256, 0, stream>>>(omax, bo, out);
}

// Round 14
// 288.974 us; speedup vs baseline: 1.0793x; 1.0793x over previous
//
#include <hip/hip_runtime.h>

// ---------------------------------------------------------------------------
// AttentionTemporalEncoder on MI355X (gfx950)
// B=32, T=512, HIDDEN=1024, NH=16, HD=64
//
// R27: resubmission of R26 (bench infra failed: "container failed twice";
// no kernel-side error). Consolidation on the best-measured structure:
//  - 3-round gemm1 (grid 768, balanced XCD mapping, dead-K/V-block exit),
//    NO tail kernel: the 2-round+tail variants (R22/R25) measured equal or
//    worse totals twice — tail node + launch ate the 26us of gemm1 savings.
//  - OcT aliases QT (-32 MB). Safe: each attn block reads only its own
//    (b,q0,hd) QT region, fully retired before its end-of-kernel OcT
//    stores to that same region; gemm2 reads after attn. (Passed in R25.)
//  - Pipeline: scan (mask permutation) -> prep (permuted xP, zero tails)
//    -> gemm1 -> attn (compacted keys, nt=ceil(Tc/64)) -> gemm2 -> final.
// ---------------------------------------------------------------------------

typedef _Float16 half8 __attribute__((ext_vector_type(8)));
typedef _Float16 half4 __attribute__((ext_vector_type(4)));
typedef float floatx4 __attribute__((ext_vector_type(4)));
typedef unsigned uintx2 __attribute__((ext_vector_type(2)));

#define HID 1024
#define TT 512
#define NB 32
#define QSCALE 0.1803368801111244f   /* 0.125 * log2(e) */
#define SB2 72.13475204444817f       /* 50 * log2(e)    */

__device__ __forceinline__ void gload16(const void* g, void* l) {
    __builtin_amdgcn_global_load_lds(
        (const __attribute__((address_space(1))) unsigned int*)g,
        (__attribute__((address_space(3))) unsigned int*)l, 16, 0, 0);
}

// monotone float->uint key: preserves order for atomicMax; 0 is below all keys
__device__ __forceinline__ unsigned fkey(float f) {
    unsigned u = __float_as_uint(f);
    return (u & 0x80000000u) ? ~u : (u | 0x80000000u);
}
__device__ __forceinline__ float funkey(unsigned k) {
    unsigned u = (k & 0x80000000u) ? (k ^ 0x80000000u) : ~k;
    return __uint_as_float(u);
}

// ---------------------------------------------------------------------------
// scan: one block per batch. cpa[b][t] = permuted position; Tcg[b] = #unmasked.
__global__ __launch_bounds__(256) void scan_kernel(
    const int* __restrict__ mask, short* __restrict__ cpa,
    int* __restrict__ Tcg)
{
    __shared__ int wsum[4];
    const int b = blockIdx.x;
    const int* mrow = mask + b * TT;
    const int tid = threadIdx.x;
    const int lane = tid & 63, wv = tid >> 6;
    const int m0 = mrow[tid * 2] ? 1 : 0;
    const int m1 = mrow[tid * 2 + 1] ? 1 : 0;
    const int ps = m0 + m1;
    int v = ps;
    for (int d = 1; d < 64; d <<= 1) {
        int u = __shfl_up(v, d, 64);
        if (lane >= d) v += u;
    }
    if (lane == 63) wsum[wv] = v;
    __syncthreads();
    int off = 0;
    for (int i = 0; i < 4; i++) off += (i < wv) ? wsum[i] : 0;
    const int total = wsum[0] + wsum[1] + wsum[2] + wsum[3];
    const int excl0 = off + v - ps;              // unmasked in [0, 2*tid)
    const int t0 = tid * 2, t1 = t0 + 1;
    const int excl1 = excl0 + m0;
    const int p0 = m0 ? excl0 : total + (t0 - excl0);
    const int p1 = m1 ? excl1 : total + (t1 - excl1);
    cpa[(size_t)b * TT + t0] = (short)p0;
    cpa[(size_t)b * TT + t1] = (short)p1;
    if (tid == 255) Tcg[b] = total;
}

// ---------------------------------------------------------------------------
// prep: [0,4096) convw (Q sec pre-scaled), [4096,8192) xpose 64x64 writing
// permuted xP rows, [8192,8320) initmax, [8320,8324) bqs,
// [8324,8580) KT/Vb tail zero-fill (8 slices per batch, uses Tcg).
__global__ __launch_bounds__(256) void prep_kernel(
    const float* __restrict__ Wq, const float* __restrict__ Wk,
    const float* __restrict__ Wv, const float* __restrict__ Wo,
    _Float16* __restrict__ Wcat,
    const float* __restrict__ x, _Float16* __restrict__ xP,
    unsigned* __restrict__ omax,
    const float* __restrict__ bq, float* __restrict__ bqs,
    const short* __restrict__ cpa, const int* __restrict__ Tcg,
    _Float16* __restrict__ KT, _Float16* __restrict__ Vb)
{
    __shared__ float tile[64][65];
    const int bid = blockIdx.x;
    if (bid < 4096) {
        int i4 = bid * 256 + threadIdx.x;        // float4 index, 0 .. 1M
        int sec = i4 >> 18;
        int off4 = i4 & ((1 << 18) - 1);
        const float* src = (sec == 0) ? Wq : (sec == 1) ? Wk
                          : (sec == 2) ? Wv : Wo;
        float4 v = ((const float4*)src)[off4];
        if (sec == 0) {
            v.x *= QSCALE; v.y *= QSCALE; v.z *= QSCALE; v.w *= QSCALE;
        }
        half4 h = {(_Float16)v.x, (_Float16)v.y, (_Float16)v.z, (_Float16)v.w};
        *(half4*)(Wcat + (size_t)i4 * 4) = h;
    } else if (bid < 8192) {
        int idx = bid - 4096;                    // 32 b x 16 h-tiles x 8 t-tiles
        int b = idx >> 7, h0 = ((idx >> 3) & 15) * 64, t0 = (idx & 7) * 64;
        int tx = threadIdx.x & 15, ty = threadIdx.x >> 4;   // 16x16
        const float* xb = x + ((size_t)b * HID + h0) * TT + t0;
        for (int p = 0; p < 4; p++) {
            int r = ty + 16 * p;
            float4 v = *(const float4*)(xb + (size_t)r * TT + tx * 4);
            tile[r][tx * 4 + 0] = v.x;
            tile[r][tx * 4 + 1] = v.y;
            tile[r][tx * 4 + 2] = v.z;
            tile[r][tx * 4 + 3] = v.w;
        }
        __syncthreads();
        int hc = (threadIdx.x & 7) * 8, tb = threadIdx.x >> 3;  // 8 x 32
        for (int rd = 0; rd < 2; rd++) {
            int tt = tb + 32 * rd;
            half8 pk;
            for (int k = 0; k < 8; k++)
                pk[k] = (_Float16)tile[hc + k][tt];
            short ct = cpa[b * TT + t0 + tt];
            *(half8*)(xP + ((size_t)b * TT + ct) * HID + h0 + hc) = pk;
        }
    } else if (bid < 8320) {
        omax[(bid - 8192) * 256 + threadIdx.x] = 0u;
    } else if (bid < 8324) {
        int i = (bid - 8320) * 256 + threadIdx.x;   // 0..1023
        bqs[i] = bq[i] * QSCALE;
    } else {
        // KT/Vb tail zero-fill, 8 slices per batch
        const int idx = bid - 8324;              // 0..255
        const int b = idx >> 3, sl = idx & 7;
        const int tid = threadIdx.x;
        const int Tc = Tcg[b];
        const int ce = (Tc + 63) & ~63;
        const int nrow = ce - Tc;                // 0..63
        // KT rows [Tc, ce), cols [sl*128, sl*128+128): half8 stores
        half8 z8 = {};
        for (int i = tid; i < nrow * 16; i += 256) {
            int r = i >> 4, c8 = i & 15;
            *(half8*)(KT + ((size_t)b * TT + Tc + r) * HID +
                      sl * 128 + c8 * 8) = z8;
        }
        // Vb o-rows [sl*128, (sl+1)*128), cols [Tc, ce): scalar
        const int o = sl * 128 + (tid >> 1);
        const int half0 = (tid & 1) * ((nrow + 1) >> 1);
        const int cnt = (tid & 1) ? (nrow - ((nrow + 1) >> 1))
                                  : ((nrow + 1) >> 1);
        _Float16* vr = Vb + ((size_t)b * HID + o) * TT + Tc + half0;
        for (int j = 0; j < cnt; j++) vr[j] = (_Float16)0.f;
    }
}

// ---------------------------------------------------------------------------
// 256x256 8-phase mainloop (R14-verified). C(256x256) += A(256xK) * B^T,
// both row-major, K contig, lda = ldb = 1024. 512 threads = 8 waves (2Mx4N),
// per-wave output 128x64 = acc[8][4]. LDS 128 KiB double-buffered; granule
// swizzle via pre-swizzled global source; counted vmcnt(10), drain 10->0.
#define PH_PRE do { \
    __builtin_amdgcn_s_barrier(); \
    asm volatile("s_waitcnt lgkmcnt(0)" ::: "memory"); \
    __builtin_amdgcn_sched_barrier(0); \
    __builtin_amdgcn_s_setprio(1); \
} while (0)

#define PH_POST(N) do { \
    __builtin_amdgcn_s_setprio(0); \
    asm volatile("s_waitcnt vmcnt(" #N ")" ::: "memory"); \
    __builtin_amdgcn_s_barrier(); \
} while (0)

#define LDA(P, MH) do { \
    const _Float16* ab_ = lds + (P) * 16384 + (MH) * 8192 + aoff; \
    af[0][0] = *(const half8*)(ab_ + pb0); \
    af[0][1] = *(const half8*)(ab_ + pb1); \
    af[1][0] = *(const half8*)(ab_ + 1024 + pb0); \
    af[1][1] = *(const half8*)(ab_ + 1024 + pb1); \
    af[2][0] = *(const half8*)(ab_ + 2048 + pb0); \
    af[2][1] = *(const half8*)(ab_ + 2048 + pb1); \
    af[3][0] = *(const half8*)(ab_ + 3072 + pb0); \
    af[3][1] = *(const half8*)(ab_ + 3072 + pb1); \
} while (0)

#define LDB(P, NH) do { \
    const _Float16* bb_ = lds + 32768 + (P) * 16384 + (NH) * 8192 + boff; \
    bf[NH][0][0] = *(const half8*)(bb_ + pb0); \
    bf[NH][0][1] = *(const half8*)(bb_ + pb1); \
    bf[NH][1][0] = *(const half8*)(bb_ + 1024 + pb0); \
    bf[NH][1][1] = *(const half8*)(bb_ + 1024 + pb1); \
} while (0)

#define MFMAQ(MH, NH) do { \
    _Pragma("unroll") \
    for (int j_ = 0; j_ < 4; ++j_) { \
        _Pragma("unroll") \
        for (int n_ = 0; n_ < 2; ++n_) { \
            floatx4 c_ = acc[(MH) * 4 + j_][(NH) * 2 + n_]; \
            c_ = __builtin_amdgcn_mfma_f32_16x16x32_f16( \
                af[j_][0], bf[NH][n_][0], c_, 0, 0, 0); \
            c_ = __builtin_amdgcn_mfma_f32_16x16x32_f16( \
                af[j_][1], bf[NH][n_][1], c_, 0, 0, 0); \
            acc[(MH) * 4 + j_][(NH) * 2 + n_] = c_; \
        } \
    } \
} while (0)

#define STAGE_A(P, MH, K0) do { \
    _Float16* d_ = lds + (P) * 16384 + (MH) * 8192 + wst; \
    gload16(ag + (MH) * 65536 + (K0), d_); \
    gload16(ag + 131072 + (MH) * 65536 + (K0), d_ + 4096); \
} while (0)

#define STAGE_B(P, NH, K0) do { \
    _Float16* d_ = lds + 32768 + (P) * 16384 + (NH) * 8192 + wst; \
    gload16(bg + (NH) * 32768 + (K0), d_); \
    gload16(bg + 131072 + (NH) * 32768 + (K0), d_ + 4096); \
} while (0)

__device__ __forceinline__ void mainloop256(
    const _Float16* __restrict__ Ag,   // A + m0*1024 (rows m, K contig)
    const _Float16* __restrict__ Bg,   // act + n0*1024 (rows n, K contig)
    _Float16* lds, floatx4 acc[8][4], int tid)
{
    const int lane = tid & 63;
    const int w = tid >> 6, wr = w >> 2, wc = w & 3;
    const int l15 = lane & 15, quad = lane >> 4;
    const int pa = quad ^ (l15 & 7);
    const int pb0 = pa * 8, pb1 = (pa ^ 4) * 8;
    const int aoff = (wr * 64 + l15) * 64;
    const int boff = (wc * 32 + l15) * 64;
    const int wst = w * 512;                    // wave-uniform LDS stage base
    const int r = tid >> 3;                     // 0..63
    const int sg = (tid & 7) ^ (r & 7);         // pre-swizzled source granule
    const int nbase = ((r >> 5) << 6) + (r & 31);
    const _Float16* ag = Ag + (size_t)r * 1024 + sg * 8;
    const _Float16* bg = Bg + (size_t)nbase * 1024 + sg * 8;

    half8 af[4][2], bf[2][2][2];

    STAGE_A(0, 0, 0); STAGE_B(0, 0, 0); STAGE_B(0, 1, 0); STAGE_A(0, 1, 0);
    STAGE_A(1, 0, 64); STAGE_B(1, 0, 64); STAGE_B(1, 1, 64);
    asm volatile("s_waitcnt vmcnt(10)" ::: "memory");
    __builtin_amdgcn_s_barrier();

    for (int i = 0; i < 7; ++i) {
        const int kb = i * 128 + 64;
        const int kn0 = kb + 64, kn1 = kb + 128;
        LDA(0, 0); LDB(0, 0); STAGE_A(1, 1, kb);
        PH_PRE; MFMAQ(0, 0); PH_POST(10);
        LDB(0, 1);            STAGE_A(0, 0, kn0);
        PH_PRE; MFMAQ(0, 1); PH_POST(10);
        LDA(0, 1);            STAGE_B(0, 0, kn0);
        PH_PRE; MFMAQ(1, 1); PH_POST(10);
                              STAGE_B(0, 1, kn0);
        PH_PRE; MFMAQ(1, 0); PH_POST(10);
        LDA(1, 0); LDB(1, 0); STAGE_A(0, 1, kn0);
        PH_PRE; MFMAQ(0, 0); PH_POST(10);
        LDB(1, 1);            STAGE_A(1, 0, kn1);
        PH_PRE; MFMAQ(0, 1); PH_POST(10);
        LDA(1, 1);            STAGE_B(1, 0, kn1);
        PH_PRE; MFMAQ(1, 1); PH_POST(10);
                              STAGE_B(1, 1, kn1);
        PH_PRE; MFMAQ(1, 0); PH_POST(10);
    }
    LDA(0, 0); LDB(0, 0); STAGE_A(1, 1, 960);
    PH_PRE; MFMAQ(0, 0); PH_POST(10);
    LDB(0, 1);
    PH_PRE; MFMAQ(0, 1); PH_POST(8);
    LDA(0, 1);
    PH_PRE; MFMAQ(1, 1); PH_POST(6);
    PH_PRE; MFMAQ(1, 0); PH_POST(4);
    LDA(1, 0); LDB(1, 0);
    PH_PRE; MFMAQ(0, 0); PH_POST(2);
    LDB(1, 1);
    PH_PRE; MFMAQ(0, 1); PH_POST(0);
    LDA(1, 1);
    PH_PRE; MFMAQ(1, 1); MFMAQ(1, 0);
    __builtin_amdgcn_s_setprio(0);
}

// gemm1. 1-D grid 768. Balanced mapping: xcd = id&7, k = slot/12,
// n0i = k&1, bb = xcd*4 + (k>>1). Single B source xP (permuted tokens).
__global__ __launch_bounds__(512, 2) void gemm1_kernel(
    const _Float16* __restrict__ Wcat,
    const float* __restrict__ bqs, const float* __restrict__ bk,
    const float* __restrict__ bv,
    const _Float16* __restrict__ xP,
    _Float16* __restrict__ QT, _Float16* __restrict__ KT,
    _Float16* __restrict__ Vb, const int* __restrict__ Tcg)
{
    __shared__ __align__(16) _Float16 smem[65536];   // 128 KiB
    const int tid = threadIdx.x;
    const int id = blockIdx.x;
    const int xcd = id & 7, slot = id >> 3;      // slot 0..95
    const int k = slot / 12;                     // 0..7
    const int m0 = (slot % 12) * 256;
    const int n0 = (k & 1) * 256;
    const int bb = xcd * 4 + (k >> 1);
    const int lane = tid & 63;
    const int w = tid >> 6, wr = w >> 2, wc = w & 3;
    const int l15 = lane & 15, quad = lane >> 4;

    const int sec = m0 >> 10;          // 0=q 1=k 2=v (uniform per block)
    const int Tc = Tcg[bb];
    if (sec > 0 && n0 >= ((Tc + 255) & ~255)) return;   // dead K/V tile

    floatx4 acc[8][4] = {};
    mainloop256(Wcat + (size_t)m0 * 1024,
                xP + ((size_t)bb * TT + n0) * HID, smem, acc, tid);
    __syncthreads();

    const int mo = m0 & 1023;

    if (sec < 2) {
        const float* bias = (sec == 0) ? bqs : bk;
        _Float16* dst = (sec == 0) ? QT : KT;
        _Float16* tr = smem;                       // [256][136] halves
        for (int h = 0; h < 2; ++h) {
            if (wr == h) {
                for (int mi = 0; mi < 8; ++mi) {
                    float bs[4];
                    for (int rr = 0; rr < 4; ++rr)
                        bs[rr] = bias[mo + h * 128 + mi * 16 + quad * 4 + rr];
                    for (int ni = 0; ni < 4; ++ni) {
                        half4 pk;
                        for (int rr = 0; rr < 4; ++rr)
                            pk[rr] = (_Float16)(acc[mi][ni][rr] + bs[rr]);
                        *(half4*)(tr + (wc * 64 + ni * 16 + l15) * 136 +
                                  mi * 16 + quad * 4) = pk;
                    }
                }
            }
            __syncthreads();
            const int row = tid >> 4, off = (tid & 15) * 8;
            for (int s = 0; s < 8; ++s) {
                int trow = n0 + row + 32 * s;
                uint4 v = *(uint4*)(tr + (row + 32 * s) * 136 + off);
                if (sec == 0 || trow < Tc)
                    *(uint4*)(dst + ((size_t)bb * TT + trow) * HID +
                              mo + h * 128 + off) = v;
            }
            __syncthreads();
        }
    } else {
        for (int mi = 0; mi < 8; ++mi) {
            float bs[4];
            for (int rr = 0; rr < 4; ++rr)
                bs[rr] = bv[mo + wr * 128 + mi * 16 + quad * 4 + rr];
            for (int ni = 0; ni < 4; ++ni) {
                int t = n0 + wc * 64 + ni * 16 + l15;   // already compacted
                if (t >= Tc) continue;
                for (int rr = 0; rr < 4; ++rr) {
                    int o = mo + wr * 128 + mi * 16 + quad * 4 + rr;
                    Vb[((size_t)bb * HID + o) * TT + t] =
                        (_Float16)(acc[mi][ni][rr] + bs[rr]);
                }
            }
        }
    }
}

// ---------------------------------------------------------------------------
// attention: 8-wave 512-thread blocks, 256 q-rows each, grid 1024.
// K/V are compacted to the first Tc[b] columns; loop nt = ceil(Tc/64) tiles;
// tail columns >= Tc clamped to -50 (K/V tails are zero-filled by prep).
// NOTE: OcT aliases QT — each block reads its own (b,q0,hd) QT region fully
// (retired to LDS/registers before the barriers) before its end-of-kernel
// OcT stores to that same region; gemm2 reads only after attn completes.
__global__ __launch_bounds__(512, 4) void attn_kernel(
    const _Float16* __restrict__ QT, const _Float16* __restrict__ KT,
    const _Float16* __restrict__ Vb, const int* __restrict__ Tcg,
    _Float16* __restrict__ OcT)
{
    __shared__ __align__(16) _Float16 kvbuf[4 * 4096];   // Q stage / K,V dbuf
    __shared__ __align__(16) _Float16 ps[2 * 8192];      // [qt][128 q][64 t]
    __shared__ __align__(16) float msf[2][64];           // clamp hi per t

    const int id = blockIdx.x;
    const int xcd = id & 7, slot = id >> 3;      // slot 0..127
    const int grp = xcd + 8 * (slot >> 1);       // 0..511 = hd + 16*b
    const int q0 = (slot & 1) * 256;
    const int hd = grp & 15, b = grp >> 4;
    const int tid = threadIdx.x;
    const int lane = tid & 63, wid = tid >> 6;   // wid 0..7
    const int l15 = lane & 15, quad = lane >> 4;

    const _Float16* QTb = QT + ((size_t)b * TT + q0) * HID + hd * 64;
    const _Float16* KTb = KT + (size_t)b * TT * HID + hd * 64;
    const _Float16* Vbb = Vb + ((size_t)b * HID + hd * 64) * TT;
    const int Tc = Tcg[b];
    const int nt = (Tc + 63) >> 6;

    const int srow = lane >> 3;                 // 0..7 == row&7
    const int sg = (lane & 7) ^ srow;
    const int pa = quad ^ (l15 & 7);
    const int pz = l15 & 7;

    // stage 256 Q rows (32 KB) into kvbuf, then lift fragments to registers
    for (int p = 0; p < 4; p++) {
        int r = p * 64 + wid * 8 + srow;
        gload16(QTb + (size_t)r * HID + sg * 8,
                kvbuf + (p * 64 + wid * 8) * 64);
    }
    __syncthreads();
    half8 bq[2][2];
    for (int qt = 0; qt < 2; qt++) {
        int qr = qt * 128 + wid * 16 + l15;
        bq[qt][0] = *(half8*)(kvbuf + qr * 64 + pa * 8);
        bq[qt][1] = *(half8*)(kvbuf + qr * 64 + (pa ^ 4) * 8);
    }
    __syncthreads();

    auto stage = [&](int jcn, int bufn) {
        int t0n = jcn * 64;
        _Float16* kd = kvbuf + bufn * 4096;
        _Float16* vd = kvbuf + (2 + bufn) * 4096;
        int r = wid * 8 + srow;
        gload16(KTb + (size_t)(t0n + r) * HID + sg * 8, kd + (wid * 8) * 64);
        gload16(Vbb + (size_t)r * TT + t0n + sg * 8, vd + (wid * 8) * 64);
        if (tid < 64) msf[bufn][tid] = (t0n + tid < Tc) ? SB2 : -SB2;
    };

    stage(0, 0);

    floatx4 oacc[2][4] = {};
    float rs[2] = {0.f, 0.f};
    const float lo = -SB2;

    for (int jc = 0; jc < nt; jc++) {
        const int cur = jc & 1;
        __syncthreads();
        if (jc < nt - 1) stage(jc + 1, 1 - cur);

        const _Float16* ks = kvbuf + cur * 4096;
        const _Float16* vs = kvbuf + (2 + cur) * 4096;

        for (int jt = 0; jt < 4; jt++) {
            half8 ka0 = *(half8*)(ks + (jt * 16 + l15) * 64 + pa * 8);
            half8 ka1 = *(half8*)(ks + (jt * 16 + l15) * 64 + (pa ^ 4) * 8);
            floatx4 hi = *(floatx4*)(&msf[cur][jt * 16 + quad * 4]);
            for (int qt = 0; qt < 2; qt++) {
                floatx4 sc = {0.f, 0.f, 0.f, 0.f};
                sc = __builtin_amdgcn_mfma_f32_16x16x32_f16(ka0, bq[qt][0], sc, 0, 0, 0);
                sc = __builtin_amdgcn_mfma_f32_16x16x32_f16(ka1, bq[qt][1], sc, 0, 0, 0);
                float e0 = __builtin_amdgcn_exp2f(fminf(fmaxf(sc[0], lo), hi[0]));
                float e1 = __builtin_amdgcn_exp2f(fminf(fmaxf(sc[1], lo), hi[1]));
                float e2 = __builtin_amdgcn_exp2f(fminf(fmaxf(sc[2], lo), hi[2]));
                float e3 = __builtin_amdgcn_exp2f(fminf(fmaxf(sc[3], lo), hi[3]));
                rs[qt] += (e0 + e1) + (e2 + e3);
                unsigned uA = __builtin_bit_cast(
                    unsigned, __builtin_amdgcn_cvt_pkrtz(e0, e1));
                unsigned uB = __builtin_bit_cast(
                    unsigned, __builtin_amdgcn_cvt_pkrtz(e2, e3));
                uintx2 uv = {uA, uB};
                half4 pk = __builtin_bit_cast(half4, uv);
                int g = jt * 2 + (quad >> 1);
                *(half4*)(ps + qt * 8192 + (wid * 16 + l15) * 64 + (g ^ pz) * 8 +
                          (quad & 1) * 4) = pk;
            }
        }
        for (int kc = 0; kc < 2; kc++) {
            int g = kc * 4 + quad;
            half8 bv8[4];
            for (int d4 = 0; d4 < 4; d4++)
                bv8[d4] = *(half8*)(vs + (d4 * 16 + l15) * 64 + (g ^ pz) * 8);
            for (int qt = 0; qt < 2; qt++) {
                half8 ap = *(half8*)(ps + qt * 8192 + (wid * 16 + l15) * 64 +
                                     (g ^ pz) * 8);
                for (int d4 = 0; d4 < 4; d4++)
                    oacc[qt][d4] = __builtin_amdgcn_mfma_f32_16x16x32_f16(
                        ap, bv8[d4], oacc[qt][d4], 0, 0, 0);
            }
        }
    }

    for (int qt = 0; qt < 2; qt++) {
        float s = rs[qt];
        s += __shfl_xor(s, 16, 64);
        s += __shfl_xor(s, 32, 64);
        s = 1.0f / s;
        float inv[4];
        for (int r = 0; r < 4; r++) inv[r] = __shfl(s, quad * 4 + r, 64);
        for (int d4 = 0; d4 < 4; d4++)
            for (int r = 0; r < 4; r++) {
                int t = q0 + qt * 128 + wid * 16 + quad * 4 + r;
                int c = hd * 64 + d4 * 16 + l15;
                OcT[((size_t)b * TT + t) * HID + c] =
                    (_Float16)(oacc[qt][d4][r] * inv[r]);
            }
    }
}

// ---------------------------------------------------------------------------
// gemm2. 1-D grid 256, XCD-clustered (4 m-tiles per n-group).
__global__ __launch_bounds__(512, 2) void gemm2_kernel(
    const _Float16* __restrict__ Wo16, const _Float16* __restrict__ OcT,
    unsigned* __restrict__ omax)
{
    __shared__ __align__(16) _Float16 smem[65536];
    _Float16* lds = smem;
    const int tid = threadIdx.x;
    const int id = blockIdx.x;
    const int xcd = id & 7, slot = id >> 3;      // slot 0..31
    const int grp = xcd + 8 * (slot >> 2);       // 0..63 = n0i + 2*b
    const int m0 = (slot & 3) * 256;
    const int n0 = (grp & 1) * 256;
    const int bb = grp >> 1;
    const int lane = tid & 63;
    const int w = tid >> 6, wr = w >> 2;
    const int l15 = lane & 15, quad = lane >> 4;

    floatx4 acc[8][4] = {};
    mainloop256(Wo16 + (size_t)m0 * 1024,
                OcT + ((size_t)bb * TT + n0) * HID, lds, acc, tid);

    for (int mi = 0; mi < 8; ++mi)
        for (int rr = 0; rr < 4; ++rr) {
            float v = acc[mi][0][rr];
            v = fmaxf(v, acc[mi][1][rr]);
            v = fmaxf(v, acc[mi][2][rr]);
            v = fmaxf(v, acc[mi][3][rr]);
            for (int d = 1; d < 16; d <<= 1)
                v = fmaxf(v, __shfl_xor(v, d, 64));
            if (l15 == 0) {
                int o = m0 + wr * 128 + mi * 16 + quad * 4 + rr;
                atomicMax(&omax[bb * HID + o], fkey(v));
            }
        }
}

__global__ __launch_bounds__(256) void final_kernel(
    const unsigned* __restrict__ omax, const float* __restrict__ bo,
    float* __restrict__ out)
{
    int i = blockIdx.x * 256 + threadIdx.x;   // 0 .. 32767
    out[i] = funkey(omax[i]) + bo[i & 1023];
}

// ---------------------------------------------------------------------------
extern "C" void kernel_launch(void* const* d_in, const int* in_sizes, int n_in,
                              void* d_out, int out_size, void* d_ws, size_t ws_size,
                              hipStream_t stream)
{
    const float* x  = (const float*)d_in[0];
    const int* mask = (const int*)d_in[1];
    const float* Wq = (const float*)d_in[2];
    const float* bq = (const float*)d_in[3];
    const float* Wk = (const float*)d_in[4];
    const float* bk = (const float*)d_in[5];
    const float* Wv = (const float*)d_in[6];
    const float* bv = (const float*)d_in[7];
    const float* Wo = (const float*)d_in[8];
    const float* bo = (const float*)d_in[9];
    float* out = (float*)d_out;

    char* ws = (char*)d_ws;
    _Float16* Wcat = (_Float16*)(ws);                      //   8 MiB (q,k,v,o)
    _Float16* xP   = (_Float16*)(ws + (8ull  << 20));      //  32 MiB (permuted)
    _Float16* QT   = (_Float16*)(ws + (40ull << 20));      //  32 MiB
    _Float16* KT   = (_Float16*)(ws + (72ull << 20));      //  32 MiB
    _Float16* Vb   = (_Float16*)(ws + (104ull << 20));     //  32 MiB
    _Float16* OcT  = QT;    // alias: attn reads QT fully before writing OcT
    unsigned* omax = (unsigned*)(ws + (136ull << 20));     // 128 KiB
    float*    bqs  = (float*)(ws + (136ull << 20) + (128ull << 10)); // 4 KiB
    short*    cpa  = (short*)(ws + (136ull << 20) + (132ull << 10)); // 32 KiB
    int*      Tcg  = (int*)  (ws + (136ull << 20) + (164ull << 10)); // 128 B

    scan_kernel<<<32, 256, 0, stream>>>(mask, cpa, Tcg);
    prep_kernel<<<8580, 256, 0, stream>>>(Wq, Wk, Wv, Wo, Wcat, x, xP,
                                          omax, bq, bqs, cpa, Tcg, KT, Vb);
    gemm1_kernel<<<768, 512, 0, stream>>>(Wcat, bqs, bk, bv, xP,
                                          QT, KT, Vb, Tcg);
    attn_kernel<<<1024, 512, 0, stream>>>(QT, KT, Vb, Tcg, OcT);
    gemm2_kernel<<<256, 512, 0, stream>>>(Wcat + (3ull << 20), OcT, omax);
    final_kernel<<<128, 256, 0, stream>>>(omax, bo, out);
}